// Round 1
// baseline (395.093 us; speedup 1.0000x reference)
//
#include <hip/hip_runtime.h>
#include <hip/hip_bf16.h>

using bf16 = __hip_bfloat16;
typedef __attribute__((ext_vector_type(8))) short bf16x8;   // 8 bf16 = 4 VGPR
typedef __attribute__((ext_vector_type(4))) float f32x4;    // MFMA C/D frag

#define DEVI __device__ __forceinline__

constexpr int Bn = 2, Sn = 2048, Dn = 2048, Hn = 16, DHn = 128;
constexpr int Mn = Bn * Sn;   // 4096

DEVI void gload_lds16(const bf16* g, bf16* l) {
  __builtin_amdgcn_global_load_lds(
      (__attribute__((address_space(1))) void*)g,
      (__attribute__((address_space(3))) void*)l,
      16, 0, 0);
}

// ---------------- f32 -> bf16 convert (vectorized 8/thread) ----------------
__global__ __launch_bounds__(256) void cvt_bf16_k(const float* __restrict__ in,
                                                  bf16* __restrict__ out, int n8) {
  int i = blockIdx.x * 256 + threadIdx.x;
  if (i >= n8) return;
  const float4* p = (const float4*)in + (size_t)i * 2;
  float4 a = p[0], b = p[1];
  union { bf16 h[8]; bf16x8 v; } u;
  u.h[0] = __float2bfloat16(a.x); u.h[1] = __float2bfloat16(a.y);
  u.h[2] = __float2bfloat16(a.z); u.h[3] = __float2bfloat16(a.w);
  u.h[4] = __float2bfloat16(b.x); u.h[5] = __float2bfloat16(b.y);
  u.h[6] = __float2bfloat16(b.z); u.h[7] = __float2bfloat16(b.w);
  *((bf16x8*)out + i) = u.v;
}

// ---------------- GEMM: C[M,N] = A[M,K] * W[N,K]^T  (both K-contig) --------
// BM=BN=128, BK=64, 256 thr = 4 waves (2x2), wave does 64x64 = 4x4 frags.
template <int OUTF32>
__global__ __launch_bounds__(256, 2) void gemm_bt(const bf16* __restrict__ A,
                                                  const bf16* __restrict__ W,
                                                  void* __restrict__ Cv) {
  constexpr int BK = 64;
  constexpr int K = 2048, N = 2048;
  __shared__ bf16 sAB[2 * 128 * BK];   // 32 KB
  bf16* sA = sAB;
  bf16* sB = sAB + 128 * BK;

  const int bn = blockIdx.x, bm = blockIdx.y;
  const size_t z = blockIdx.z;
  const bf16* Bp = W + z * (size_t)(2048 * 2048);

  const int t = threadIdx.x;
  const int lane = t & 63, wave = t >> 6;
  const int wr = wave >> 1, wc = wave & 1;
  const int lr = lane & 15, lg = lane >> 4;

  const int sr = t >> 3, sc = (t & 7) * 8;   // staging: 16B/thread, 32 rows/issue

  f32x4 acc[4][4];
  const f32x4 zf = {0.f, 0.f, 0.f, 0.f};
#pragma unroll
  for (int i = 0; i < 4; ++i)
#pragma unroll
    for (int j = 0; j < 4; ++j) acc[i][j] = zf;

  const bf16* ga = A + (size_t)(bm * 128 + sr) * K + sc;
  const bf16* gb = Bp + (size_t)(bn * 128 + sr) * K + sc;
  bf16* la = sA + sr * BK + sc;   // == sA + t*8  (wave-linear)
  bf16* lb = sB + sr * BK + sc;

  for (int kt = 0; kt < K; kt += BK) {
    __syncthreads();
#pragma unroll
    for (int i = 0; i < 4; ++i) gload_lds16(ga + (size_t)i * 32 * K + kt, la + i * 32 * BK);
#pragma unroll
    for (int i = 0; i < 4; ++i) gload_lds16(gb + (size_t)i * 32 * K + kt, lb + i * 32 * BK);
    __syncthreads();

    bf16x8 af[4][2], bfr[4][2];
#pragma unroll
    for (int mm = 0; mm < 4; ++mm)
#pragma unroll
      for (int kk = 0; kk < 2; ++kk)
        af[mm][kk] = *(const bf16x8*)(sA + (wr * 64 + mm * 16 + lr) * BK + kk * 32 + lg * 8);
#pragma unroll
    for (int nn = 0; nn < 4; ++nn)
#pragma unroll
      for (int kk = 0; kk < 2; ++kk)
        bfr[nn][kk] = *(const bf16x8*)(sB + (wc * 64 + nn * 16 + lr) * BK + kk * 32 + lg * 8);
#pragma unroll
    for (int kk = 0; kk < 2; ++kk)
#pragma unroll
      for (int mm = 0; mm < 4; ++mm)
#pragma unroll
        for (int nn = 0; nn < 4; ++nn)
          acc[mm][nn] = __builtin_amdgcn_mfma_f32_16x16x32_bf16(af[mm][kk], bfr[nn][kk],
                                                                acc[mm][nn], 0, 0, 0);
  }

  const int r0 = bm * 128 + wr * 64, c0 = bn * 128 + wc * 64;
#pragma unroll
  for (int mm = 0; mm < 4; ++mm)
#pragma unroll
    for (int nn = 0; nn < 4; ++nn) {
      const int rr = r0 + mm * 16 + lg * 4;
      const int cc = c0 + nn * 16 + lr;
#pragma unroll
      for (int r = 0; r < 4; ++r) {
        float v = acc[mm][nn][r];
        if (OUTF32) {
          ((float*)Cv)[(size_t)(rr + r) * N + cc] = v;
        } else {
          bf16* C = (bf16*)Cv + z * (size_t)(4096 * 2048);
          C[(size_t)(rr + r) * N + cc] = __float2bfloat16(v);
        }
      }
    }
}

// ---------------- V transpose: per (b,h)  V[2048,128] -> VT[128,2048] ------
__global__ __launch_bounds__(256, 2) void transpose_v(const bf16* __restrict__ V,
                                                      bf16* __restrict__ VT) {
  __shared__ bf16 tile[128 * 128];   // 32 KB, chunk-XOR-swizzled
  const int kt = blockIdx.x, bh = blockIdx.y;
  const bf16* Vh = V + (size_t)bh * (Sn * DHn);
  bf16* VTh = VT + (size_t)bh * (DHn * Sn);
  const int t = threadIdx.x;
  const int rr = t >> 4, cc = t & 15;
#pragma unroll
  for (int i = 0; i < 8; ++i) {
    int r = rr + i * 16;
    int ch = cc ^ ((r >> 3) & 7);
    *(bf16x8*)(tile + r * 128 + ch * 8) =
        *(const bf16x8*)(Vh + (size_t)(kt * 128 + r) * DHn + cc * 8);
  }
  __syncthreads();
  const int dr = t >> 4, li = t & 15;
#pragma unroll
  for (int i = 0; i < 8; ++i) {
    int dh = dr + i * 16;
    union { bf16 h[8]; bf16x8 v; } u;
#pragma unroll
    for (int j = 0; j < 8; ++j) {
      int k = li * 8 + j;
      int ch = (dh >> 3) ^ ((k >> 3) & 7);
      u.h[j] = tile[k * 128 + ch * 8 + (dh & 7)];
    }
    *(bf16x8*)(VTh + (size_t)dh * Sn + kt * 128 + li * 8) = u.v;
  }
}

// ---------------- causal flash attention, one block per (qb, bh) -----------
// 4 waves x 32 q-rows, KBLK=64, Q in regs, K/VT staged via global_load_lds.
__global__ __launch_bounds__(256, 2) void attn_k(const bf16* __restrict__ Q,
                                                 const bf16* __restrict__ K,
                                                 const bf16* __restrict__ VT,
                                                 bf16* __restrict__ Mg) {
  __shared__ bf16 smem[24576];   // 48 KB
  bf16* sK = smem;               // [64][128]
  bf16* sVT = smem + 8192;       // [128][64]
  bf16* sP = smem + 16384;       // 4 x [32][64]

  const int qb = 15 - blockIdx.x;   // descending work for load balance
  const int bh = blockIdx.y;
  const bf16* Qh = Q + (size_t)bh * (Sn * DHn);
  const bf16* Kh = K + (size_t)bh * (Sn * DHn);
  const bf16* VTh = VT + (size_t)bh * (DHn * Sn);

  const int t = threadIdx.x, wave = t >> 6, lane = t & 63;
  const int lr = lane & 15, lg = lane >> 4;
  const int q0 = qb * 128 + wave * 32;

  bf16x8 qf[2][4];
#pragma unroll
  for (int mm = 0; mm < 2; ++mm)
#pragma unroll
    for (int kk = 0; kk < 4; ++kk)
      qf[mm][kk] = *(const bf16x8*)(Qh + (size_t)(q0 + mm * 16 + lr) * DHn + kk * 32 + lg * 8);

  const f32x4 zf = {0.f, 0.f, 0.f, 0.f};
  f32x4 o[2][8];
#pragma unroll
  for (int mm = 0; mm < 2; ++mm)
#pragma unroll
    for (int d = 0; d < 8; ++d) o[mm][d] = zf;
  float mrun[2][4], lrun[2][4];
#pragma unroll
  for (int mm = 0; mm < 2; ++mm)
#pragma unroll
    for (int r = 0; r < 4; ++r) { mrun[mm][r] = -3e38f; lrun[mm][r] = 0.f; }

  const int skr = t >> 4, skc = (t & 15) * 8;   // K staging
  const int svr = t >> 3, svc = (t & 7) * 8;    // VT staging

  const int nkt = qb * 2 + 2;
  for (int kt = 0; kt < nkt; ++kt) {
    __syncthreads();
#pragma unroll
    for (int i = 0; i < 4; ++i)
      gload_lds16(Kh + (size_t)(kt * 64 + skr + i * 16) * DHn + skc,
                  sK + (skr + i * 16) * DHn + skc);
#pragma unroll
    for (int i = 0; i < 4; ++i)
      gload_lds16(VTh + (size_t)(svr + i * 32) * Sn + kt * 64 + svc,
                  sVT + (svr + i * 32) * 64 + svc);
    __syncthreads();

    // S = Q K^T  (per wave: 2 m-frags x 4 n-frags)
    f32x4 sfr[2][4];
#pragma unroll
    for (int mm = 0; mm < 2; ++mm)
#pragma unroll
      for (int nn = 0; nn < 4; ++nn) sfr[mm][nn] = zf;
#pragma unroll
    for (int kk = 0; kk < 4; ++kk)
#pragma unroll
      for (int nn = 0; nn < 4; ++nn) {
        bf16x8 kf = *(const bf16x8*)(sK + (nn * 16 + lr) * DHn + kk * 32 + lg * 8);
#pragma unroll
        for (int mm = 0; mm < 2; ++mm)
          sfr[mm][nn] = __builtin_amdgcn_mfma_f32_16x16x32_bf16(qf[mm][kk], kf, sfr[mm][nn], 0, 0, 0);
      }

    const bool maskt = (kt >= qb * 2);
#pragma unroll
    for (int mm = 0; mm < 2; ++mm) {
      float pv[4][4];
#pragma unroll
      for (int nn = 0; nn < 4; ++nn)
#pragma unroll
        for (int r = 0; r < 4; ++r) {
          float v = sfr[mm][nn][r] * (1.0f / 128.0f);
          if (maskt) {
            int kg = kt * 64 + nn * 16 + lr;
            int qg = q0 + mm * 16 + lg * 4 + r;
            if (kg > qg) v = -1e30f;
          }
          pv[nn][r] = v;
        }
      float mnew[4], alpha[4], rsum[4];
#pragma unroll
      for (int r = 0; r < 4; ++r) {
        float rm = fmaxf(fmaxf(pv[0][r], pv[1][r]), fmaxf(pv[2][r], pv[3][r]));
        rm = fmaxf(rm, __shfl_xor(rm, 1));
        rm = fmaxf(rm, __shfl_xor(rm, 2));
        rm = fmaxf(rm, __shfl_xor(rm, 4));
        rm = fmaxf(rm, __shfl_xor(rm, 8));
        mnew[r] = fmaxf(mrun[mm][r], rm);
        alpha[r] = __expf(mrun[mm][r] - mnew[r]);
        mrun[mm][r] = mnew[r];
        rsum[r] = 0.f;
      }
#pragma unroll
      for (int nn = 0; nn < 4; ++nn)
#pragma unroll
        for (int r = 0; r < 4; ++r) {
          float p = __expf(pv[nn][r] - mnew[r]);
          pv[nn][r] = p;
          rsum[r] += p;
        }
#pragma unroll
      for (int r = 0; r < 4; ++r) {
        float s = rsum[r];
        s += __shfl_xor(s, 1); s += __shfl_xor(s, 2);
        s += __shfl_xor(s, 4); s += __shfl_xor(s, 8);
        lrun[mm][r] = lrun[mm][r] * alpha[r] + s;
      }
#pragma unroll
      for (int d = 0; d < 8; ++d)
#pragma unroll
        for (int r = 0; r < 4; ++r) o[mm][d][r] *= alpha[r];
#pragma unroll
      for (int nn = 0; nn < 4; ++nn)
#pragma unroll
        for (int r = 0; r < 4; ++r)
          sP[wave * 2048 + (mm * 16 + lg * 4 + r) * 64 + nn * 16 + lr] =
              __float2bfloat16(pv[nn][r]);
    }

    // O += P V   (P from per-wave LDS, A-frag layout; V^T rows from LDS)
    bf16x8 pf[2][2];
#pragma unroll
    for (int mm = 0; mm < 2; ++mm)
#pragma unroll
      for (int kk = 0; kk < 2; ++kk)
        pf[mm][kk] = *(const bf16x8*)(sP + wave * 2048 + (mm * 16 + lr) * 64 + kk * 32 + lg * 8);
#pragma unroll
    for (int d = 0; d < 8; ++d)
#pragma unroll
      for (int kk = 0; kk < 2; ++kk) {
        bf16x8 vf = *(const bf16x8*)(sVT + (d * 16 + lr) * 64 + kk * 32 + lg * 8);
#pragma unroll
        for (int mm = 0; mm < 2; ++mm)
          o[mm][d] = __builtin_amdgcn_mfma_f32_16x16x32_bf16(pf[mm][kk], vf, o[mm][d], 0, 0, 0);
      }
  }

  __syncthreads();
  bf16* sO = smem;   // [128][128] reuses sK+sVT
#pragma unroll
  for (int mm = 0; mm < 2; ++mm) {
    float inv[4];
#pragma unroll
    for (int r = 0; r < 4; ++r) inv[r] = 1.0f / lrun[mm][r];
#pragma unroll
    for (int d = 0; d < 8; ++d)
#pragma unroll
      for (int r = 0; r < 4; ++r)
        sO[(wave * 32 + mm * 16 + lg * 4 + r) * 128 + d * 16 + lr] =
            __float2bfloat16(o[mm][d][r] * inv[r]);
  }
  __syncthreads();
  const int b = bh >> 4, h = bh & 15;
  bf16* Mh = Mg + ((size_t)(b * Sn + qb * 128)) * Dn + h * DHn;
#pragma unroll
  for (int i = 0; i < 8; ++i) {
    int row = (t >> 4) + i * 16, seg = (t & 15) * 8;
    *(bf16x8*)(Mh + (size_t)row * Dn + seg) = *(const bf16x8*)(sO + row * 128 + seg);
  }
}

// ---------------------------------------------------------------------------
extern "C" void kernel_launch(void* const* d_in, const int* in_sizes, int n_in,
                              void* d_out, int out_size, void* d_ws, size_t ws_size,
                              hipStream_t stream) {
  const float* x = (const float*)d_in[0];
  const float* Wq = (const float*)d_in[1];
  const float* Wk = (const float*)d_in[2];
  const float* Wv = (const float*)d_in[3];
  const float* Wo = (const float*)d_in[4];
  float* out = (float*)d_out;

  char* ws = (char*)d_ws;
  bf16* xb = (bf16*)ws;            ws += (size_t)Mn * Dn * 2;        // 16 MB
  bf16* Wb = (bf16*)ws;            ws += (size_t)4 * Dn * Dn * 2;    // 32 MB (q,k,v,o)
  bf16* QKV = (bf16*)ws;           ws += (size_t)3 * Mn * Dn * 2;    // 48 MB
  bf16* VT = (bf16*)ws;            ws += (size_t)Bn * Hn * DHn * Sn * 2; // 16 MB
  bf16* Mg = (bf16*)ws;            ws += (size_t)Mn * Dn * 2;        // 16 MB

  const int nx8 = Mn * Dn / 8;     // 1048576
  const int nw8 = Dn * Dn / 8;     // 524288
  cvt_bf16_k<<<nx8 / 256, 256, 0, stream>>>(x, xb, nx8);
  cvt_bf16_k<<<nw8 / 256, 256, 0, stream>>>(Wq, Wb + 0 * (size_t)Dn * Dn, nw8);
  cvt_bf16_k<<<nw8 / 256, 256, 0, stream>>>(Wk, Wb + 1 * (size_t)Dn * Dn, nw8);
  cvt_bf16_k<<<nw8 / 256, 256, 0, stream>>>(Wv, Wb + 2 * (size_t)Dn * Dn, nw8);
  cvt_bf16_k<<<nw8 / 256, 256, 0, stream>>>(Wo, Wb + 3 * (size_t)Dn * Dn, nw8);

  // Q,K,V = x @ W{q,k,v}^T  -> bf16
  gemm_bt<0><<<dim3(16, 32, 3), 256, 0, stream>>>(xb, Wb, (void*)QKV);

  // per-head V transpose
  transpose_v<<<dim3(16, 32), 256, 0, stream>>>(QKV + 2 * (size_t)Mn * Dn, VT);

  // causal attention -> merged [4096, 2048] bf16
  attn_k<<<dim3(16, 32), 256, 0, stream>>>(QKV, QKV + (size_t)Mn * Dn, VT, Mg);

  // out = merged @ Wo^T -> f32
  gemm_bt<1><<<dim3(16, 32, 1), 256, 0, stream>>>(Mg, Wb + 3 * (size_t)Dn * Dn, (void*)out);
}

// Round 2
// 288.477 us; speedup vs baseline: 1.3696x; 1.3696x over previous
//
#include <hip/hip_runtime.h>
#include <hip/hip_bf16.h>

using bf16 = __hip_bfloat16;
typedef __attribute__((ext_vector_type(8))) short bf16x8;   // 8 bf16 = 4 VGPR
typedef __attribute__((ext_vector_type(4))) float f32x4;    // MFMA C/D frag

#define DEVI __device__ __forceinline__

constexpr int Bn = 2, Sn = 2048, Dn = 2048, Hn = 16, DHn = 128;
constexpr int Mn = Bn * Sn;   // 4096

DEVI void gload_lds16(const bf16* g, bf16* l) {
  __builtin_amdgcn_global_load_lds(
      (__attribute__((address_space(1))) void*)g,
      (__attribute__((address_space(3))) void*)l,
      16, 0, 0);
}

// ---------------- f32 -> bf16 convert (vectorized 8/thread) ----------------
__global__ __launch_bounds__(256) void cvt_bf16_k(const float* __restrict__ in,
                                                  bf16* __restrict__ out, int n8) {
  int i = blockIdx.x * 256 + threadIdx.x;
  if (i >= n8) return;
  const float4* p = (const float4*)in + (size_t)i * 2;
  float4 a = p[0], b = p[1];
  union { bf16 h[8]; bf16x8 v; } u;
  u.h[0] = __float2bfloat16(a.x); u.h[1] = __float2bfloat16(a.y);
  u.h[2] = __float2bfloat16(a.z); u.h[3] = __float2bfloat16(a.w);
  u.h[4] = __float2bfloat16(b.x); u.h[5] = __float2bfloat16(b.y);
  u.h[6] = __float2bfloat16(b.z); u.h[7] = __float2bfloat16(b.w);
  *((bf16x8*)out + i) = u.v;
}

// ---------------- GEMM: C[M,N] = A[M,K] * W[N,K]^T  (both K-contig) --------
// BM=BN=128, BK=64, 256 thr = 4 waves (2x2), wave does 64x64 = 4x4 frags.
template <int OUTF32>
__global__ __launch_bounds__(256, 2) void gemm_bt(const bf16* __restrict__ A,
                                                  const bf16* __restrict__ W,
                                                  void* __restrict__ Cv) {
  constexpr int BK = 64;
  constexpr int K = 2048, N = 2048;
  __shared__ bf16 sAB[2 * 128 * BK];   // 32 KB
  bf16* sA = sAB;
  bf16* sB = sAB + 128 * BK;

  const int bn = blockIdx.x, bm = blockIdx.y;
  const size_t z = blockIdx.z;
  const bf16* Bp = W + z * (size_t)(2048 * 2048);

  const int t = threadIdx.x;
  const int lane = t & 63, wave = t >> 6;
  const int wr = wave >> 1, wc = wave & 1;
  const int lr = lane & 15, lg = lane >> 4;

  const int sr = t >> 3, sc = (t & 7) * 8;   // staging: 16B/thread, 32 rows/issue

  f32x4 acc[4][4];
  const f32x4 zf = {0.f, 0.f, 0.f, 0.f};
#pragma unroll
  for (int i = 0; i < 4; ++i)
#pragma unroll
    for (int j = 0; j < 4; ++j) acc[i][j] = zf;

  const bf16* ga = A + (size_t)(bm * 128 + sr) * K + sc;
  const bf16* gb = Bp + (size_t)(bn * 128 + sr) * K + sc;
  bf16* la = sA + sr * BK + sc;   // == sA + t*8  (wave-linear)
  bf16* lb = sB + sr * BK + sc;

  for (int kt = 0; kt < K; kt += BK) {
    __syncthreads();
#pragma unroll
    for (int i = 0; i < 4; ++i) gload_lds16(ga + (size_t)i * 32 * K + kt, la + i * 32 * BK);
#pragma unroll
    for (int i = 0; i < 4; ++i) gload_lds16(gb + (size_t)i * 32 * K + kt, lb + i * 32 * BK);
    __syncthreads();

    bf16x8 af[4][2], bfr[4][2];
#pragma unroll
    for (int mm = 0; mm < 4; ++mm)
#pragma unroll
      for (int kk = 0; kk < 2; ++kk)
        af[mm][kk] = *(const bf16x8*)(sA + (wr * 64 + mm * 16 + lr) * BK + kk * 32 + lg * 8);
#pragma unroll
    for (int nn = 0; nn < 4; ++nn)
#pragma unroll
      for (int kk = 0; kk < 2; ++kk)
        bfr[nn][kk] = *(const bf16x8*)(sB + (wc * 64 + nn * 16 + lr) * BK + kk * 32 + lg * 8);
#pragma unroll
    for (int kk = 0; kk < 2; ++kk)
#pragma unroll
      for (int mm = 0; mm < 4; ++mm)
#pragma unroll
        for (int nn = 0; nn < 4; ++nn)
          acc[mm][nn] = __builtin_amdgcn_mfma_f32_16x16x32_bf16(af[mm][kk], bfr[nn][kk],
                                                                acc[mm][nn], 0, 0, 0);
  }

  const int r0 = bm * 128 + wr * 64, c0 = bn * 128 + wc * 64;
#pragma unroll
  for (int mm = 0; mm < 4; ++mm)
#pragma unroll
    for (int nn = 0; nn < 4; ++nn) {
      const int rr = r0 + mm * 16 + lg * 4;
      const int cc = c0 + nn * 16 + lr;
#pragma unroll
      for (int r = 0; r < 4; ++r) {
        float v = acc[mm][nn][r];
        if (OUTF32) {
          ((float*)Cv)[(size_t)(rr + r) * N + cc] = v;
        } else {
          bf16* C = (bf16*)Cv + z * (size_t)(4096 * 2048);
          C[(size_t)(rr + r) * N + cc] = __float2bfloat16(v);
        }
      }
    }
}

// ---------------- V transpose: per (b,h)  V[2048,128] -> VT[128,2048] ------
__global__ __launch_bounds__(256, 2) void transpose_v(const bf16* __restrict__ V,
                                                      bf16* __restrict__ VT) {
  __shared__ bf16 tile[128 * 128];   // 32 KB, chunk-XOR-swizzled
  const int kt = blockIdx.x, bh = blockIdx.y;
  const bf16* Vh = V + (size_t)bh * (Sn * DHn);
  bf16* VTh = VT + (size_t)bh * (DHn * Sn);
  const int t = threadIdx.x;
  const int rr = t >> 4, cc = t & 15;
#pragma unroll
  for (int i = 0; i < 8; ++i) {
    int r = rr + i * 16;
    int ch = cc ^ ((r >> 3) & 7);
    *(bf16x8*)(tile + r * 128 + ch * 8) =
        *(const bf16x8*)(Vh + (size_t)(kt * 128 + r) * DHn + cc * 8);
  }
  __syncthreads();
  const int dr = t >> 4, li = t & 15;
#pragma unroll
  for (int i = 0; i < 8; ++i) {
    int dh = dr + i * 16;
    union { bf16 h[8]; bf16x8 v; } u;
#pragma unroll
    for (int j = 0; j < 8; ++j) {
      int k = li * 8 + j;
      int ch = (dh >> 3) ^ ((k >> 3) & 7);
      u.h[j] = tile[k * 128 + ch * 8 + (dh & 7)];
    }
    *(bf16x8*)(VTh + (size_t)dh * Sn + kt * 128 + li * 8) = u.v;
  }
}

// ---------------- causal flash attention v2 --------------------------------
// QBLK=64, 4 waves x 16 q-rows. Block pairs qb=j with qb=31-j (33 tiles each,
// perfectly balanced). 2-phase double-buffered K/VT staging via
// global_load_lds with XOR chunk swizzle (linear LDS dest, pre-swizzled
// global source; swizzled ds_read).
__global__ __launch_bounds__(256, 2) void attn_k2(const bf16* __restrict__ Q,
                                                  const bf16* __restrict__ K,
                                                  const bf16* __restrict__ VT,
                                                  bf16* __restrict__ Mg) {
  __shared__ bf16 smem[36864];         // 72 KB
  bf16* sK0 = smem;                    // [64][128] swizzled
  bf16* sK1 = smem + 8192;
  bf16* sV0 = smem + 16384;            // [128][64] swizzled
  bf16* sV1 = smem + 24576;
  bf16* sP  = smem + 32768;            // 4 waves x [16][64] swizzled
  bf16* sO  = smem;                    // epilogue reuse [64][128] swizzled

  const int j = blockIdx.x;            // pair index 0..15
  const int bh = blockIdx.y;
  const bf16* Qh = Q + (size_t)bh * (Sn * DHn);
  const bf16* Kh = K + (size_t)bh * (Sn * DHn);
  const bf16* VTh = VT + (size_t)bh * (DHn * Sn);
  const int b = bh >> 4, h = bh & 15;

  const int t = threadIdx.x, wave = t >> 6, lane = t & 63;
  const int lr = lane & 15, lg = lane >> 4;

  auto STAGE = [&](int buf, int kt) {
    bf16* dK = buf ? sK1 : sK0;
    bf16* dV = buf ? sV1 : sV0;
#pragma unroll
    for (int i = 0; i < 4; ++i) {
      int c = i * 256 + t;
      int row = c >> 4, c16 = c & 15;
      gload_lds16(Kh + (size_t)(kt * 64 + row) * DHn + ((c16 ^ (row & 7)) * 8),
                  dK + c * 8);
    }
#pragma unroll
    for (int i = 0; i < 4; ++i) {
      int c = i * 256 + t;
      int row = c >> 3, c8 = c & 7;
      gload_lds16(VTh + (size_t)row * Sn + kt * 64 + ((c8 ^ (row & 7)) * 8),
                  dV + c * 8);
    }
  };

  const f32x4 zf = {0.f, 0.f, 0.f, 0.f};

  for (int pi = 0; pi < 2; ++pi) {
    const int qb = pi ? (31 - j) : j;
    const int nt = qb + 1;
    const int q0 = qb * 64 + wave * 16;

    bf16x8 qf[4];
#pragma unroll
    for (int kk = 0; kk < 4; ++kk)
      qf[kk] = *(const bf16x8*)(Qh + (size_t)(q0 + lr) * DHn + kk * 32 + lg * 8);

    f32x4 o[8];
#pragma unroll
    for (int d = 0; d < 8; ++d) o[d] = zf;
    float mrun[4], lrun[4];
#pragma unroll
    for (int r = 0; r < 4; ++r) { mrun[r] = -3e38f; lrun[r] = 0.f; }

    STAGE(0, 0);
    __syncthreads();   // drains vmcnt(0): buf0 ready
    int cur = 0;

    for (int kt = 0; kt < nt; ++kt) {
      if (kt + 1 < nt) STAGE(cur ^ 1, kt + 1);   // prefetch in flight over compute

      bf16* sKc = cur ? sK1 : sK0;
      bf16* sVc = cur ? sV1 : sV0;

      // S = Q K^T
      f32x4 sfr[4];
#pragma unroll
      for (int nn = 0; nn < 4; ++nn) sfr[nn] = zf;
#pragma unroll
      for (int kk = 0; kk < 4; ++kk)
#pragma unroll
        for (int nn = 0; nn < 4; ++nn) {
          int row = nn * 16 + lr;
          int ch = (kk * 4 + lg) ^ (row & 7);
          bf16x8 kf = *(const bf16x8*)(sKc + row * DHn + ch * 8);
          sfr[nn] = __builtin_amdgcn_mfma_f32_16x16x32_bf16(qf[kk], kf, sfr[nn], 0, 0, 0);
        }

      // online softmax (rows: lg*4+r, cols: nn*16+lr)
      const bool maskt = (kt == nt - 1);
      float pv[4][4];
#pragma unroll
      for (int nn = 0; nn < 4; ++nn)
#pragma unroll
        for (int r = 0; r < 4; ++r) {
          float v = sfr[nn][r] * (1.0f / 128.0f);
          if (maskt) {
            int kg = kt * 64 + nn * 16 + lr;
            int qg = q0 + lg * 4 + r;
            if (kg > qg) v = -1e30f;
          }
          pv[nn][r] = v;
        }
      float mnew[4], alpha[4], rsum[4];
#pragma unroll
      for (int r = 0; r < 4; ++r) {
        float rm = fmaxf(fmaxf(pv[0][r], pv[1][r]), fmaxf(pv[2][r], pv[3][r]));
        rm = fmaxf(rm, __shfl_xor(rm, 1));
        rm = fmaxf(rm, __shfl_xor(rm, 2));
        rm = fmaxf(rm, __shfl_xor(rm, 4));
        rm = fmaxf(rm, __shfl_xor(rm, 8));
        mnew[r] = fmaxf(mrun[r], rm);
        alpha[r] = __expf(mrun[r] - mnew[r]);
        mrun[r] = mnew[r];
        rsum[r] = 0.f;
      }
#pragma unroll
      for (int nn = 0; nn < 4; ++nn)
#pragma unroll
        for (int r = 0; r < 4; ++r) {
          float p = __expf(pv[nn][r] - mnew[r]);
          pv[nn][r] = p;
          rsum[r] += p;
        }
#pragma unroll
      for (int r = 0; r < 4; ++r) {
        float s = rsum[r];
        s += __shfl_xor(s, 1); s += __shfl_xor(s, 2);
        s += __shfl_xor(s, 4); s += __shfl_xor(s, 8);
        lrun[r] = lrun[r] * alpha[r] + s;
      }
#pragma unroll
      for (int d = 0; d < 8; ++d)
#pragma unroll
        for (int r = 0; r < 4; ++r) o[d][r] *= alpha[r];

      // P -> LDS (swizzled), per-wave region
#pragma unroll
      for (int nn = 0; nn < 4; ++nn)
#pragma unroll
        for (int r = 0; r < 4; ++r) {
          int row = lg * 4 + r;
          int chk = (nn * 2 + (lr >> 3)) ^ (row & 7);
          sP[wave * 1024 + row * 64 + chk * 8 + (lr & 7)] = __float2bfloat16(pv[nn][r]);
        }

      // O += P V
      bf16x8 pf[2];
#pragma unroll
      for (int kk = 0; kk < 2; ++kk) {
        int ch = (kk * 4 + lg) ^ (lr & 7);
        pf[kk] = *(const bf16x8*)(sP + wave * 1024 + lr * 64 + ch * 8);
      }
#pragma unroll
      for (int d = 0; d < 8; ++d)
#pragma unroll
        for (int kk = 0; kk < 2; ++kk) {
          int vrow = d * 16 + lr;
          int vch = (kk * 4 + lg) ^ (vrow & 7);
          bf16x8 vf = *(const bf16x8*)(sVc + vrow * 64 + vch * 8);
          o[d] = __builtin_amdgcn_mfma_f32_16x16x32_bf16(pf[kk], vf, o[d], 0, 0, 0);
        }

      __syncthreads();   // drains prefetch vmcnt + all ds reads of cur
      cur ^= 1;
    }

    // epilogue: normalize, stage to LDS (swizzled), coalesced global write
    float inv[4];
#pragma unroll
    for (int r = 0; r < 4; ++r) inv[r] = 1.0f / lrun[r];
#pragma unroll
    for (int d = 0; d < 8; ++d)
#pragma unroll
      for (int r = 0; r < 4; ++r) {
        int row = wave * 16 + lg * 4 + r;
        int col = d * 16 + lr;
        int chk = ((col >> 3) ^ (row & 7));
        sO[row * 128 + chk * 8 + (col & 7)] = __float2bfloat16(o[d][r] * inv[r]);
      }
    __syncthreads();
    bf16* Mh = Mg + ((size_t)(b * Sn + qb * 64)) * Dn + h * DHn;
#pragma unroll
    for (int i = 0; i < 4; ++i) {
      int row = (t >> 4) + i * 16;
      int c16 = t & 15;
      *(bf16x8*)(Mh + (size_t)row * Dn + c16 * 8) =
          *(const bf16x8*)(sO + row * 128 + ((c16 ^ (row & 7)) * 8));
    }
    __syncthreads();   // sO region is re-staged by next pass
  }
}

// ---------------------------------------------------------------------------
extern "C" void kernel_launch(void* const* d_in, const int* in_sizes, int n_in,
                              void* d_out, int out_size, void* d_ws, size_t ws_size,
                              hipStream_t stream) {
  const float* x = (const float*)d_in[0];
  const float* Wq = (const float*)d_in[1];
  const float* Wk = (const float*)d_in[2];
  const float* Wv = (const float*)d_in[3];
  const float* Wo = (const float*)d_in[4];
  float* out = (float*)d_out;

  char* ws = (char*)d_ws;
  bf16* xb = (bf16*)ws;            ws += (size_t)Mn * Dn * 2;        // 16 MB
  bf16* Wb = (bf16*)ws;            ws += (size_t)4 * Dn * Dn * 2;    // 32 MB (q,k,v,o)
  bf16* QKV = (bf16*)ws;           ws += (size_t)3 * Mn * Dn * 2;    // 48 MB
  bf16* VT = (bf16*)ws;            ws += (size_t)Bn * Hn * DHn * Sn * 2; // 16 MB
  bf16* Mg = (bf16*)ws;            ws += (size_t)Mn * Dn * 2;        // 16 MB

  const int nx8 = Mn * Dn / 8;     // 1048576
  const int nw8 = Dn * Dn / 8;     // 524288
  cvt_bf16_k<<<nx8 / 256, 256, 0, stream>>>(x, xb, nx8);
  cvt_bf16_k<<<nw8 / 256, 256, 0, stream>>>(Wq, Wb + 0 * (size_t)Dn * Dn, nw8);
  cvt_bf16_k<<<nw8 / 256, 256, 0, stream>>>(Wk, Wb + 1 * (size_t)Dn * Dn, nw8);
  cvt_bf16_k<<<nw8 / 256, 256, 0, stream>>>(Wv, Wb + 2 * (size_t)Dn * Dn, nw8);
  cvt_bf16_k<<<nw8 / 256, 256, 0, stream>>>(Wo, Wb + 3 * (size_t)Dn * Dn, nw8);

  // Q,K,V = x @ W{q,k,v}^T  -> bf16
  gemm_bt<0><<<dim3(16, 32, 3), 256, 0, stream>>>(xb, Wb, (void*)QKV);

  // per-head V transpose
  transpose_v<<<dim3(16, 32), 256, 0, stream>>>(QKV + 2 * (size_t)Mn * Dn, VT);

  // causal attention -> merged [4096, 2048] bf16
  attn_k2<<<dim3(16, 32), 256, 0, stream>>>(QKV, QKV + (size_t)Mn * Dn, VT, Mg);

  // out = merged @ Wo^T -> f32
  gemm_bt<1><<<dim3(16, 32, 1), 256, 0, stream>>>(Mg, Wb + 3 * (size_t)Dn * Dn, (void*)out);
}